// Round 17
// baseline (176.697 us; speedup 1.0000x reference)
//
#include <hip/hip_runtime.h>
#include <hip/hip_bf16.h>
#include <stdint.h>

#define D_MODEL 1024
#define NHEAD   16
#define HDIM    64
#define BATCH   4
#define SEQ     2048
#define NTOK    (BATCH*SEQ)   // 8192

typedef __bf16          b16x8 __attribute__((ext_vector_type(8)));
typedef unsigned short  u16x8 __attribute__((ext_vector_type(8)));
typedef unsigned short  u16x4 __attribute__((ext_vector_type(4)));
typedef float           f32x4 __attribute__((ext_vector_type(4)));

__device__ __forceinline__ unsigned short f2b(float f) {
  union { float f; uint32_t u; } c; c.f = f;
  return (unsigned short)((c.u + 0x7FFFu + ((c.u >> 16) & 1u)) >> 16);
}

// packed 2xf32 -> 2xbf16 (attn P-pack only)
__device__ __forceinline__ uint32_t cvtpk(float lo, float hi) {
  uint32_t r;
  asm("v_cvt_pk_bf16_f32 %0, %1, %2" : "=v"(r) : "v"(lo), "v"(hi));
  return r;
}

// fp32x8 -> bf16x8 via native casts (compiler emits v_cvt_pk_bf16_f32 pairs)
__device__ __forceinline__ b16x8 cv8(f32x4 a, f32x4 b) {
  b16x8 r;
#pragma unroll
  for (int i = 0; i < 4; i++) { r[i] = (__bf16)a[i]; r[i + 4] = (__bf16)b[i]; }
  return r;
}

// async global->LDS, 16B per lane; dest = wave-uniform base + lane*16
__device__ __forceinline__ void glds16(const void* g, void* l) {
  __builtin_amdgcn_global_load_lds(
      (const __attribute__((address_space(1))) unsigned int*)g,
      (__attribute__((address_space(3))) unsigned int*)l, 16, 0, 0);
}

// ---------------- W pack: fp32 -> bf16 pre-swizzled 8KB DMA images ----------------
// image = 128 rows x 64B; slot s of row r holds content chunk s ^ ((r>>1)&3).
// proj DMA-copies linearly, reads with matching XOR (rule #21). Verified r8/r12.
__global__ __launch_bounds__(256, 8)
void wpack_kernel(const float* __restrict__ Wq, const float* __restrict__ Wk,
                  const float* __restrict__ Wv, unsigned short* __restrict__ wsp) {
  int bid = blockIdx.x;            // 768 = 3(which) x 8(tn) x 32(kt)
  int which = bid >> 8;
  int tn = (bid >> 5) & 7;
  int kt = bid & 31;
  const float* W = (which == 0) ? Wq : ((which == 1) ? Wk : Wv);
  int t = threadIdx.x;
  int r = t >> 1;
  int sw0 = (t & 1) * 2;
  char* dst = (char*)wsp + (size_t)bid * 8192 + t * 32;
  const float* src = W + (size_t)(tn * 128 + r) * D_MODEL + kt * 32;
#pragma unroll
  for (int i = 0; i < 2; i++) {
    int s = (sw0 + i) ^ ((r >> 1) & 3);
    f32x4 a = *(const f32x4*)(src + s * 8);
    f32x4 b = *(const f32x4*)(src + s * 8 + 4);
    u16x8 pk;
#pragma unroll
    for (int j = 0; j < 4; j++) { pk[j] = f2b(a[j]); pk[j + 4] = f2b(b[j]); }
    *(u16x8*)(dst + i * 16) = pk;
  }
}

// ---------------- proj GEMM v2: 3-stage counted-vmcnt pipeline (T3/T4) ----------------
// r17 change: raw s_barrier + explicit s_waitcnt vmcnt(N) so prefetch DMA
// stays in flight ACROSS barriers (m201/m218 pattern; counted-vs-drain0 was
// +38-73%). 3 LDS stages (72KB, 2 blocks/CU), prefetch distance 2 -> each
// tile's DMA gets ~2 compute-steps (~480cy) of cover vs ~1 before.
// Accounting: prologue stages t0,t1 (12 loads). Iter k: vmcnt(6) [t_k done,
// t_{k+1} in flight] -> s_barrier -> sched_barrier -> issue t_{k+2} ->
// compute t_k. In-loop LDS is DMA-only (no ds_writes), so the raw barrier
// needs no lgkmcnt drain for cross-wave correctness.
__global__ __launch_bounds__(256, 2)
void proj_gemm_f32a(const float* __restrict__ q, const float* __restrict__ k,
                    const float* __restrict__ v, const unsigned short* __restrict__ wsp,
                    unsigned short* __restrict__ qp, unsigned short* __restrict__ kp,
                    unsigned short* __restrict__ vt) {
  __shared__ __align__(16) char lds[3][24576];   // per stage: A 16KB fp32 | B 8KB bf16

  int bid = blockIdx.x;
  int swz = (bid & 7) * 192 + (bid >> 3);      // bijective XCD swizzle, 1536 % 8 == 0
  int which = swz >> 9;
  int rr = swz & 511;
  int tm = rr >> 3, tn = rr & 7;

  const float* X = (which == 0) ? q : ((which == 1) ? k : v);
  const char* Bpack = (const char*)wsp + (size_t)((which * 8 + tn) * 32) * 8192;

  int tid  = threadIdx.x;
  int lane = tid & 63;
  int w    = tid >> 6;
  int g    = lane >> 4;
  int c    = lane & 15;
  int chi  = c & 7;
  int wr   = (w >> 1) * 64;
  int wc   = (w & 1) * 64;

  f32x4 acc[4][4];
#pragma unroll
  for (int m = 0; m < 4; m++)
#pragma unroll
    for (int n = 0; n < 4; n++) acc[m][n] = (f32x4){0.f, 0.f, 0.f, 0.f};

  int arowl = lane >> 3;
  int aswz  = ((lane & 7) ^ arowl) << 4;
  const char* Asrc = (const char*)(X + (size_t)(tm * 128 + w * 32 + arowl) * D_MODEL) + aswz;
  const char* Bsrc = Bpack + w * 2048 + lane * 16;

  int aoff0 = (wr + c) * 128 + ((2 * g    ^ chi) << 4);
  int aoff1 = (wr + c) * 128 + (((2*g+1) ^ chi) << 4);
  int rboff = 16384 + (wc + c) * 64 + ((g ^ ((c >> 1) & 3)) << 4);

  char* b0 = lds[0];
  char* b1 = lds[1];
  char* b2 = lds[2];

  // STAGE(tile kt -> buffer p): 6 glds16 per thread-slice (wave-linear dests)
#define STAGE(p, kt)                                                               \
  do {                                                                             \
    glds16(Asrc + (size_t)0 * 8 * D_MODEL * 4 + (kt) * 128, (p) + w * 4096 + 0 * 1024); \
    glds16(Asrc + (size_t)1 * 8 * D_MODEL * 4 + (kt) * 128, (p) + w * 4096 + 1 * 1024); \
    glds16(Asrc + (size_t)2 * 8 * D_MODEL * 4 + (kt) * 128, (p) + w * 4096 + 2 * 1024); \
    glds16(Asrc + (size_t)3 * 8 * D_MODEL * 4 + (kt) * 128, (p) + w * 4096 + 3 * 1024); \
    glds16(Bsrc + (size_t)(kt) * 8192,        (p) + 16384 + w * 2048);              \
    glds16(Bsrc + (size_t)(kt) * 8192 + 1024, (p) + 16384 + w * 2048 + 1024);       \
  } while (0)

  STAGE(b0, 0);
  STAGE(b1, 1);

  for (int kt = 0; kt < 32; kt++) {
    if (kt < 31) asm volatile("s_waitcnt vmcnt(6)" ::: "memory");
    else         asm volatile("s_waitcnt vmcnt(0)" ::: "memory");
    __builtin_amdgcn_s_barrier();
    __builtin_amdgcn_sched_barrier(0);
    if (kt < 30) STAGE(b2, kt + 2);      // into the slot read two iters ago

    const char* buf = b0;
    b16x8 af[4];
    u16x8 bf[4];
#pragma unroll
    for (int m = 0; m < 4; m++) {
      f32x4 a0 = *(const f32x4*)(buf + aoff0 + m * 2048);
      f32x4 a1 = *(const f32x4*)(buf + aoff1 + m * 2048);
      af[m] = cv8(a0, a1);
    }
#pragma unroll
    for (int n = 0; n < 4; n++)
      bf[n] = *(const u16x8*)(buf + rboff + n * 1024);
#pragma unroll
    for (int m = 0; m < 4; m++)
#pragma unroll
      for (int n = 0; n < 4; n++)
        acc[m][n] = __builtin_amdgcn_mfma_f32_16x16x32_bf16(
            af[m], __builtin_bit_cast(b16x8, bf[n]), acc[m][n], 0, 0, 0);

    char* t = b0; b0 = b1; b1 = b2; b2 = t;
  }
#undef STAGE

  int cbase = tn * 128 + wc;
  int rbase = tm * 128 + wr;
  if (which < 2) {
    unsigned short* OutP = (which == 0) ? qp : kp;
    float scale = (which == 0) ? 0.18033688f : 1.0f;   // 0.125*log2(e)
#pragma unroll
    for (int m = 0; m < 4; m++)
#pragma unroll
      for (int n = 0; n < 4; n++) {
        int e = cbase + n * 16 + c;
        int h = e >> 6, dh = e & 63;
#pragma unroll
        for (int j = 0; j < 4; j++) {
          int i = rbase + m * 16 + g * 4 + j;
          int b = i >> 11, s = i & 2047;
          OutP[(((size_t)(b * NHEAD + h)) * SEQ + s) * HDIM + dh] =
              f2b(acc[m][n][j] * scale);
        }
      }
  } else {
#pragma unroll
    for (int m = 0; m < 4; m++)
#pragma unroll
      for (int n = 0; n < 4; n++) {
        int e = cbase + n * 16 + c;
        int h = e >> 6, dh = e & 63;
        int i0 = rbase + m * 16 + g * 4;
        int b = i0 >> 11, s0 = i0 & 2047;
        u16x4 pk;
#pragma unroll
        for (int j = 0; j < 4; j++) pk[j] = f2b(acc[m][n][j]);
        *(u16x4*)&vt[(((size_t)(b * NHEAD + h)) * HDIM + dh) * SEQ + s0] = pk;
      }
  }
}

// ---------------- flash attention v6: DMA-staged K/V (unchanged from r16) ----------------
#define KVB 64
__global__ __launch_bounds__(256, 4)
void attn_kernel(const unsigned short* __restrict__ qp,
                 const unsigned short* __restrict__ kp,
                 const unsigned short* __restrict__ vt,
                 float* __restrict__ out) {
  __shared__ __align__(16) char lds[2][16384];  // per buf: K tile 8KB | V tile 8KB

  int bid = blockIdx.x;
  int swz = (bid & 7) * 128 + (bid >> 3);  // bijective XCD swizzle, 1024 % 8 == 0
  int bh = swz >> 4;   // 0..63
  int qb = swz & 15;

  int tid  = threadIdx.x;
  int lane = tid & 63;
  int w    = tid >> 6;
  int g    = lane >> 4;
  int c    = lane & 15;
  int chi  = c & 7;

  const unsigned short* Kg = kp + (size_t)bh * SEQ * HDIM;
  const unsigned short* Vg = vt + (size_t)bh * HDIM * SEQ;

  int q0 = qb * 128 + w * 32;
  u16x8 qf[2][2];
#pragma unroll
  for (int qg = 0; qg < 2; qg++)
#pragma unroll
    for (int h = 0; h < 2; h++)
      qf[qg][h] = *(const u16x8*)&qp[((size_t)bh * SEQ + q0 + qg * 16 + c) * HDIM + h * 32 + g * 8];

  f32x4 o[4][2];
#pragma unroll
  for (int d = 0; d < 4; d++)
#pragma unroll
    for (int qg = 0; qg < 2; qg++) o[d][qg] = (f32x4){0.f, 0.f, 0.f, 0.f};
  f32x4 lacc[2];
  lacc[0] = (f32x4){0.f, 0.f, 0.f, 0.f};
  lacc[1] = (f32x4){0.f, 0.f, 0.f, 0.f};

  const u16x8 ones = {0x3F80, 0x3F80, 0x3F80, 0x3F80, 0x3F80, 0x3F80, 0x3F80, 0x3F80};

  int koffA = c * 128 + ((g * 16) ^ (chi << 4));
  int koffB = c * 128 + (((64 + g * 16)) ^ (chi << 4));
  int voff[2][2];
#pragma unroll
  for (int w2 = 0; w2 < 2; w2++) {
    int b0 = w2 * 64 + g * 8;
    voff[w2][0] = 8192 + c * 128 + ((((b0      >> 4) ^ chi) << 4) + (b0 & 15));
    voff[w2][1] = 8192 + c * 128 + (((((b0+32) >> 4) ^ chi) << 4) + (b0 & 15));
  }

  int srow   = lane >> 3;
  int schunk = ((lane & 7) ^ srow) * 8;
  const unsigned short* KgL = Kg + (size_t)(w * 16 + srow) * HDIM + schunk;
  const unsigned short* VgL = Vg + (size_t)(w * 16 + srow) * SEQ + schunk;

  glds16(KgL,            lds[0] + w * 2048);
  glds16(KgL + 8 * HDIM, lds[0] + w * 2048 + 1024);
  glds16(VgL,            lds[0] + 8192 + w * 2048);
  glds16(VgL + 8 * SEQ,  lds[0] + 8192 + w * 2048 + 1024);

  for (int t = 0; t < SEQ / KVB; t++) {
    __syncthreads();
    if (t < SEQ / KVB - 1) {
      KgL += KVB * HDIM;
      VgL += KVB;
      char* nb = lds[(t + 1) & 1];
      glds16(KgL,            nb + w * 2048);
      glds16(KgL + 8 * HDIM, nb + w * 2048 + 1024);
      glds16(VgL,            nb + 8192 + w * 2048);
      glds16(VgL + 8 * SEQ,  nb + 8192 + w * 2048 + 1024);
    }
    const char* cur = lds[t & 1];

    f32x4 sf[4][2];
    __builtin_amdgcn_s_setprio(1);
#pragma unroll
    for (int st = 0; st < 4; st++) {
      u16x8 kf0 = *(const u16x8*)(cur + koffA + st * 2048);
      u16x8 kf1 = *(const u16x8*)(cur + koffB + st * 2048);
#pragma unroll
      for (int qg = 0; qg < 2; qg++) {
        sf[st][qg] = __builtin_amdgcn_mfma_f32_16x16x32_bf16(
            __builtin_bit_cast(b16x8, kf0), __builtin_bit_cast(b16x8, qf[qg][0]),
            (f32x4){0.f, 0.f, 0.f, 0.f}, 0, 0, 0);
        sf[st][qg] = __builtin_amdgcn_mfma_f32_16x16x32_bf16(
            __builtin_bit_cast(b16x8, kf1), __builtin_bit_cast(b16x8, qf[qg][1]),
            sf[st][qg], 0, 0, 0);
      }
    }
    __builtin_amdgcn_s_setprio(0);

    union { uint32_t u[4]; u16x8 v; } pb[2][2];
#pragma unroll
    for (int qg = 0; qg < 2; qg++) {
      float p[4][4];
#pragma unroll
      for (int st = 0; st < 4; st++)
#pragma unroll
        for (int j = 0; j < 4; j++) p[st][j] = exp2f(sf[st][qg][j]);
#pragma unroll
      for (int w2 = 0; w2 < 2; w2++) {
        pb[w2][qg].u[0] = cvtpk(p[2*w2][0],   p[2*w2][1]);
        pb[w2][qg].u[1] = cvtpk(p[2*w2][2],   p[2*w2][3]);
        pb[w2][qg].u[2] = cvtpk(p[2*w2+1][0], p[2*w2+1][1]);
        pb[w2][qg].u[3] = cvtpk(p[2*w2+1][2], p[2*w2+1][3]);
      }
    }

    __builtin_amdgcn_s_setprio(1);
#pragma unroll
    for (int w2 = 0; w2 < 2; w2++) {
#pragma unroll
      for (int d = 0; d < 4; d++) {
        union { u16x4 h[2]; u16x8 v; } afu;
        afu.h[0] = *(const u16x4*)(cur + voff[w2][0] + d * 2048);
        afu.h[1] = *(const u16x4*)(cur + voff[w2][1] + d * 2048);
#pragma unroll
        for (int qg = 0; qg < 2; qg++)
          o[d][qg] = __builtin_amdgcn_mfma_f32_16x16x32_bf16(
              __builtin_bit_cast(b16x8, afu.v), __builtin_bit_cast(b16x8, pb[w2][qg].v),
              o[d][qg], 0, 0, 0);
      }
#pragma unroll
      for (int qg = 0; qg < 2; qg++)
        lacc[qg] = __builtin_amdgcn_mfma_f32_16x16x32_bf16(
            __builtin_bit_cast(b16x8, ones), __builtin_bit_cast(b16x8, pb[w2][qg].v),
            lacc[qg], 0, 0, 0);
    }
    __builtin_amdgcn_s_setprio(0);
  }

#pragma unroll
  for (int qg = 0; qg < 2; qg++) {
    float inv = 1.f / lacc[qg][0];
    float* orow = out + ((size_t)bh * SEQ + q0 + qg * 16 + c) * HDIM;
#pragma unroll
    for (int d = 0; d < 4; d++) {
      f32x4 val;
#pragma unroll
      for (int j = 0; j < 4; j++) val[j] = o[d][qg][j] * inv;
      *(f32x4*)(orow + d * 16 + g * 4) = val;
    }
  }
}

extern "C" void kernel_launch(void* const* d_in, const int* in_sizes, int n_in,
                              void* d_out, int out_size, void* d_ws, size_t ws_size,
                              hipStream_t stream) {
  const float* q  = (const float*)d_in[0];
  const float* k  = (const float*)d_in[1];
  const float* v  = (const float*)d_in[2];
  const float* Wq = (const float*)d_in[3];
  const float* Wk = (const float*)d_in[4];
  const float* Wv = (const float*)d_in[5];

  const size_t projBytes = (size_t)NTOK * D_MODEL * 2;   // 16 MB each
  unsigned short* qp  = (unsigned short*)d_ws;
  unsigned short* kp  = (unsigned short*)((char*)d_ws + projBytes);
  unsigned short* vt  = (unsigned short*)((char*)d_ws + 2 * projBytes);
  unsigned short* wsp = (unsigned short*)((char*)d_ws + 3 * projBytes);   // 6 MB
  float* out = (float*)d_out;

  hipLaunchKernelGGL(wpack_kernel, dim3(768), dim3(256), 0, stream,
                     Wq, Wk, Wv, wsp);
  hipLaunchKernelGGL(proj_gemm_f32a, dim3(1536), dim3(256), 0, stream,
                     q, k, v, wsp, qp, kp, vt);
  hipLaunchKernelGGL(attn_kernel, dim3(1024), dim3(256), 0, stream,
                     qp, kp, vt, out);
}

// Round 18
// 170.903 us; speedup vs baseline: 1.0339x; 1.0339x over previous
//
#include <hip/hip_runtime.h>
#include <hip/hip_bf16.h>
#include <stdint.h>

#define D_MODEL 1024
#define NHEAD   16
#define HDIM    64
#define BATCH   4
#define SEQ     2048
#define NTOK    (BATCH*SEQ)   // 8192

typedef __bf16          b16x8 __attribute__((ext_vector_type(8)));
typedef unsigned short  u16x8 __attribute__((ext_vector_type(8)));
typedef unsigned short  u16x4 __attribute__((ext_vector_type(4)));
typedef float           f32x4 __attribute__((ext_vector_type(4)));

__device__ __forceinline__ unsigned short f2b(float f) {
  union { float f; uint32_t u; } c; c.f = f;
  return (unsigned short)((c.u + 0x7FFFu + ((c.u >> 16) & 1u)) >> 16);
}

// packed 2xf32 -> 2xbf16 (attn P-pack only)
__device__ __forceinline__ uint32_t cvtpk(float lo, float hi) {
  uint32_t r;
  asm("v_cvt_pk_bf16_f32 %0, %1, %2" : "=v"(r) : "v"(lo), "v"(hi));
  return r;
}

// fp32x8 -> bf16x8 via native casts (compiler emits v_cvt_pk_bf16_f32 pairs)
__device__ __forceinline__ b16x8 cv8(f32x4 a, f32x4 b) {
  b16x8 r;
#pragma unroll
  for (int i = 0; i < 4; i++) { r[i] = (__bf16)a[i]; r[i + 4] = (__bf16)b[i]; }
  return r;
}

// async global->LDS, 16B per lane; dest = wave-uniform base + lane*16
__device__ __forceinline__ void glds16(const void* g, void* l) {
  __builtin_amdgcn_global_load_lds(
      (const __attribute__((address_space(1))) unsigned int*)g,
      (__attribute__((address_space(3))) unsigned int*)l, 16, 0, 0);
}

// ---------------- W pack: fp32 -> bf16 pre-swizzled 8KB DMA images ----------------
__global__ __launch_bounds__(256, 8)
void wpack_kernel(const float* __restrict__ Wq, const float* __restrict__ Wk,
                  const float* __restrict__ Wv, unsigned short* __restrict__ wsp) {
  int bid = blockIdx.x;            // 768 = 3(which) x 8(tn) x 32(kt)
  int which = bid >> 8;
  int tn = (bid >> 5) & 7;
  int kt = bid & 31;
  const float* W = (which == 0) ? Wq : ((which == 1) ? Wk : Wv);
  int t = threadIdx.x;
  int r = t >> 1;
  int sw0 = (t & 1) * 2;
  char* dst = (char*)wsp + (size_t)bid * 8192 + t * 32;
  const float* src = W + (size_t)(tn * 128 + r) * D_MODEL + kt * 32;
#pragma unroll
  for (int i = 0; i < 2; i++) {
    int s = (sw0 + i) ^ ((r >> 1) & 3);
    f32x4 a = *(const f32x4*)(src + s * 8);
    f32x4 b = *(const f32x4*)(src + s * 8 + 4);
    u16x8 pk;
#pragma unroll
    for (int j = 0; j < 4; j++) { pk[j] = f2b(a[j]); pk[j + 4] = f2b(b[j]); }
    *(u16x8*)(dst + i * 16) = pk;
  }
}

// ---------------- proj GEMM (r16 config -- best measured): A fp32 DMA, B packed ----------------
__global__ __launch_bounds__(256, 3)
void proj_gemm_f32a(const float* __restrict__ q, const float* __restrict__ k,
                    const float* __restrict__ v, const unsigned short* __restrict__ wsp,
                    unsigned short* __restrict__ qp, unsigned short* __restrict__ kp,
                    unsigned short* __restrict__ vt) {
  __shared__ __align__(16) char lds[2][24576];   // per buf: A 16KB fp32 | B 8KB bf16

  int bid = blockIdx.x;
  int swz = (bid & 7) * 192 + (bid >> 3);
  int which = swz >> 9;
  int rr = swz & 511;
  int tm = rr >> 3, tn = rr & 7;

  const float* X = (which == 0) ? q : ((which == 1) ? k : v);
  const char* Bpack = (const char*)wsp + (size_t)((which * 8 + tn) * 32) * 8192;

  int tid  = threadIdx.x;
  int lane = tid & 63;
  int w    = tid >> 6;
  int g    = lane >> 4;
  int c    = lane & 15;
  int chi  = c & 7;
  int wr   = (w >> 1) * 64;
  int wc   = (w & 1) * 64;

  f32x4 acc[4][4];
#pragma unroll
  for (int m = 0; m < 4; m++)
#pragma unroll
    for (int n = 0; n < 4; n++) acc[m][n] = (f32x4){0.f, 0.f, 0.f, 0.f};

  int arowl = lane >> 3;
  int aswz  = ((lane & 7) ^ arowl) << 4;
  const char* Asrc = (const char*)(X + (size_t)(tm * 128 + w * 32 + arowl) * D_MODEL) + aswz;
  const char* Bsrc = Bpack + w * 2048 + lane * 16;

  int aoff0 = (wr + c) * 128 + ((2 * g    ^ chi) << 4);
  int aoff1 = (wr + c) * 128 + (((2*g+1) ^ chi) << 4);
  int rboff = 16384 + (wc + c) * 64 + ((g ^ ((c >> 1) & 3)) << 4);

#pragma unroll
  for (int i = 0; i < 4; i++)
    glds16(Asrc + (size_t)i * 8 * D_MODEL * 4, lds[0] + w * 4096 + i * 1024);
  glds16(Bsrc,        lds[0] + 16384 + w * 2048);
  glds16(Bsrc + 1024, lds[0] + 16384 + w * 2048 + 1024);

  for (int kt = 0; kt < 32; kt++) {
    __syncthreads();
    if (kt < 31) {
      char* nb = lds[(kt + 1) & 1];
#pragma unroll
      for (int i = 0; i < 4; i++)
        glds16(Asrc + (size_t)i * 8 * D_MODEL * 4 + (kt + 1) * 128, nb + w * 4096 + i * 1024);
      glds16(Bsrc + (size_t)(kt + 1) * 8192,        nb + 16384 + w * 2048);
      glds16(Bsrc + (size_t)(kt + 1) * 8192 + 1024, nb + 16384 + w * 2048 + 1024);
    }
    const char* buf = lds[kt & 1];
    b16x8 af[4];
    u16x8 bf[4];
#pragma unroll
    for (int m = 0; m < 4; m++) {
      f32x4 a0 = *(const f32x4*)(buf + aoff0 + m * 2048);
      f32x4 a1 = *(const f32x4*)(buf + aoff1 + m * 2048);
      af[m] = cv8(a0, a1);
    }
#pragma unroll
    for (int n = 0; n < 4; n++)
      bf[n] = *(const u16x8*)(buf + rboff + n * 1024);
#pragma unroll
    for (int m = 0; m < 4; m++)
#pragma unroll
      for (int n = 0; n < 4; n++)
        acc[m][n] = __builtin_amdgcn_mfma_f32_16x16x32_bf16(
            af[m], __builtin_bit_cast(b16x8, bf[n]), acc[m][n], 0, 0, 0);
  }

  int cbase = tn * 128 + wc;
  int rbase = tm * 128 + wr;
  if (which < 2) {
    unsigned short* OutP = (which == 0) ? qp : kp;
    float scale = (which == 0) ? 0.18033688f : 1.0f;   // 0.125*log2(e)
#pragma unroll
    for (int m = 0; m < 4; m++)
#pragma unroll
      for (int n = 0; n < 4; n++) {
        int e = cbase + n * 16 + c;
        int h = e >> 6, dh = e & 63;
#pragma unroll
        for (int j = 0; j < 4; j++) {
          int i = rbase + m * 16 + g * 4 + j;
          int b = i >> 11, s = i & 2047;
          OutP[(((size_t)(b * NHEAD + h)) * SEQ + s) * HDIM + dh] =
              f2b(acc[m][n][j] * scale);
        }
      }
  } else {
#pragma unroll
    for (int m = 0; m < 4; m++)
#pragma unroll
      for (int n = 0; n < 4; n++) {
        int e = cbase + n * 16 + c;
        int h = e >> 6, dh = e & 63;
        int i0 = rbase + m * 16 + g * 4;
        int b = i0 >> 11, s0 = i0 & 2047;
        u16x4 pk;
#pragma unroll
        for (int j = 0; j < 4; j++) pk[j] = f2b(acc[m][n][j]);
        *(u16x4*)&vt[(((size_t)(b * NHEAD + h)) * HDIM + dh) * SEQ + s0] = pk;
      }
  }
}

// ---------------- flash attention v7: 64 q-rows/wave (LDS-traffic diet) ----------------
// r18 change: attn is LDS-READ-TRAFFIC bound (each wave re-reads the whole
// 16KB K+V tile; LDS pipe is per-CU while MFMA/VALU are per-SIMD). Doubling
// q-rows per wave (qg 2->4) halves LDS bytes per unit work. K fragments are
// hoisted to registers (read once per tile); V reads stay outside the qg
// loop. VGPR ~210 -> launch_bounds(256,2). Grid 512 = 64 bh x 8 qb x 256 rows.
#define KVB 64
__global__ __launch_bounds__(256, 2)
void attn_kernel(const unsigned short* __restrict__ qp,
                 const unsigned short* __restrict__ kp,
                 const unsigned short* __restrict__ vt,
                 float* __restrict__ out) {
  __shared__ __align__(16) char lds[2][16384];  // per buf: K tile 8KB | V tile 8KB

  int bid = blockIdx.x;
  int swz = (bid & 7) * 64 + (bid >> 3);   // bijective XCD swizzle, 512 % 8 == 0
  int bh = swz >> 3;   // 0..63
  int qb = swz & 7;

  int tid  = threadIdx.x;
  int lane = tid & 63;
  int w    = tid >> 6;
  int g    = lane >> 4;
  int c    = lane & 15;
  int chi  = c & 7;

  const unsigned short* Kg = kp + (size_t)bh * SEQ * HDIM;
  const unsigned short* Vg = vt + (size_t)bh * HDIM * SEQ;

  // ---- Q fragments (B-operand): qf[qg][h], q-rows q0+qg*16+c ----
  int q0 = qb * 256 + w * 64;
  u16x8 qf[4][2];
#pragma unroll
  for (int qg = 0; qg < 4; qg++)
#pragma unroll
    for (int h = 0; h < 2; h++)
      qf[qg][h] = *(const u16x8*)&qp[((size_t)bh * SEQ + q0 + qg * 16 + c) * HDIM + h * 32 + g * 8];

  f32x4 o[4][4];
#pragma unroll
  for (int d = 0; d < 4; d++)
#pragma unroll
    for (int qg = 0; qg < 4; qg++) o[d][qg] = (f32x4){0.f, 0.f, 0.f, 0.f};
  f32x4 lacc[4];
#pragma unroll
  for (int qg = 0; qg < 4; qg++) lacc[qg] = (f32x4){0.f, 0.f, 0.f, 0.f};

  const u16x8 ones = {0x3F80, 0x3F80, 0x3F80, 0x3F80, 0x3F80, 0x3F80, 0x3F80, 0x3F80};

  // ---- hoisted LDS read offsets (image layout identical to v6) ----
  int koffA = c * 128 + ((g * 16) ^ (chi << 4));
  int koffB = c * 128 + (((64 + g * 16)) ^ (chi << 4));
  int voff[2][2];
#pragma unroll
  for (int w2 = 0; w2 < 2; w2++) {
    int b0 = w2 * 64 + g * 8;
    voff[w2][0] = 8192 + c * 128 + ((((b0      >> 4) ^ chi) << 4) + (b0 & 15));
    voff[w2][1] = 8192 + c * 128 + (((((b0+32) >> 4) ^ chi) << 4) + (b0 & 15));
  }

  // ---- DMA staging: per-lane pre-swizzled source, lane-linear LDS dest ----
  int srow   = lane >> 3;
  int schunk = ((lane & 7) ^ srow) * 8;
  const unsigned short* KgL = Kg + (size_t)(w * 16 + srow) * HDIM + schunk;
  const unsigned short* VgL = Vg + (size_t)(w * 16 + srow) * SEQ + schunk;

  glds16(KgL,            lds[0] + w * 2048);
  glds16(KgL + 8 * HDIM, lds[0] + w * 2048 + 1024);
  glds16(VgL,            lds[0] + 8192 + w * 2048);
  glds16(VgL + 8 * SEQ,  lds[0] + 8192 + w * 2048 + 1024);

  for (int t = 0; t < SEQ / KVB; t++) {
    __syncthreads();
    if (t < SEQ / KVB - 1) {
      KgL += KVB * HDIM;
      VgL += KVB;
      char* nb = lds[(t + 1) & 1];
      glds16(KgL,            nb + w * 2048);
      glds16(KgL + 8 * HDIM, nb + w * 2048 + 1024);
      glds16(VgL,            nb + 8192 + w * 2048);
      glds16(VgL + 8 * SEQ,  nb + 8192 + w * 2048 + 1024);
    }
    const char* cur = lds[t & 1];

    // ---- K fragments once per tile into registers ----
    u16x8 kf[4][2];
#pragma unroll
    for (int st = 0; st < 4; st++) {
      kf[st][0] = *(const u16x8*)(cur + koffA + st * 2048);
      kf[st][1] = *(const u16x8*)(cur + koffB + st * 2048);
    }

    // ---- per qg: S^T = K Q^T, softmax, pack (sf live range = one qg) ----
    union { uint32_t u[4]; u16x8 v; } pb[2][4];   // [w2][qg]
#pragma unroll
    for (int qg = 0; qg < 4; qg++) {
      f32x4 sf[4];
      __builtin_amdgcn_s_setprio(1);
#pragma unroll
      for (int st = 0; st < 4; st++) {
        sf[st] = __builtin_amdgcn_mfma_f32_16x16x32_bf16(
            __builtin_bit_cast(b16x8, kf[st][0]), __builtin_bit_cast(b16x8, qf[qg][0]),
            (f32x4){0.f, 0.f, 0.f, 0.f}, 0, 0, 0);
        sf[st] = __builtin_amdgcn_mfma_f32_16x16x32_bf16(
            __builtin_bit_cast(b16x8, kf[st][1]), __builtin_bit_cast(b16x8, qf[qg][1]),
            sf[st], 0, 0, 0);
      }
      __builtin_amdgcn_s_setprio(0);
      float p[4][4];
#pragma unroll
      for (int st = 0; st < 4; st++)
#pragma unroll
        for (int j = 0; j < 4; j++) p[st][j] = exp2f(sf[st][j]);
#pragma unroll
      for (int w2 = 0; w2 < 2; w2++) {
        pb[w2][qg].u[0] = cvtpk(p[2*w2][0],   p[2*w2][1]);
        pb[w2][qg].u[1] = cvtpk(p[2*w2][2],   p[2*w2][3]);
        pb[w2][qg].u[2] = cvtpk(p[2*w2+1][0], p[2*w2+1][1]);
        pb[w2][qg].u[3] = cvtpk(p[2*w2+1][2], p[2*w2+1][3]);
      }
    }

    // ---- O^T += V^T P^T (V frags read once, reused across 4 qg); l via ones-MFMA ----
    __builtin_amdgcn_s_setprio(1);
#pragma unroll
    for (int w2 = 0; w2 < 2; w2++) {
#pragma unroll
      for (int d = 0; d < 4; d++) {
        union { u16x4 h[2]; u16x8 v; } afu;
        afu.h[0] = *(const u16x4*)(cur + voff[w2][0] + d * 2048);
        afu.h[1] = *(const u16x4*)(cur + voff[w2][1] + d * 2048);
#pragma unroll
        for (int qg = 0; qg < 4; qg++)
          o[d][qg] = __builtin_amdgcn_mfma_f32_16x16x32_bf16(
              __builtin_bit_cast(b16x8, afu.v), __builtin_bit_cast(b16x8, pb[w2][qg].v),
              o[d][qg], 0, 0, 0);
      }
#pragma unroll
      for (int qg = 0; qg < 4; qg++)
        lacc[qg] = __builtin_amdgcn_mfma_f32_16x16x32_bf16(
            __builtin_bit_cast(b16x8, ones), __builtin_bit_cast(b16x8, pb[w2][qg].v),
            lacc[qg], 0, 0, 0);
    }
    __builtin_amdgcn_s_setprio(0);
  }

  // ---- epilogue ----
#pragma unroll
  for (int qg = 0; qg < 4; qg++) {
    float inv = 1.f / lacc[qg][0];
    float* orow = out + ((size_t)bh * SEQ + q0 + qg * 16 + c) * HDIM;
#pragma unroll
    for (int d = 0; d < 4; d++) {
      f32x4 val;
#pragma unroll
      for (int j = 0; j < 4; j++) val[j] = o[d][qg][j] * inv;
      *(f32x4*)(orow + d * 16 + g * 4) = val;
    }
  }
}

extern "C" void kernel_launch(void* const* d_in, const int* in_sizes, int n_in,
                              void* d_out, int out_size, void* d_ws, size_t ws_size,
                              hipStream_t stream) {
  const float* q  = (const float*)d_in[0];
  const float* k  = (const float*)d_in[1];
  const float* v  = (const float*)d_in[2];
  const float* Wq = (const float*)d_in[3];
  const float* Wk = (const float*)d_in[4];
  const float* Wv = (const float*)d_in[5];

  const size_t projBytes = (size_t)NTOK * D_MODEL * 2;   // 16 MB each
  unsigned short* qp  = (unsigned short*)d_ws;
  unsigned short* kp  = (unsigned short*)((char*)d_ws + projBytes);
  unsigned short* vt  = (unsigned short*)((char*)d_ws + 2 * projBytes);
  unsigned short* wsp = (unsigned short*)((char*)d_ws + 3 * projBytes);   // 6 MB
  float* out = (float*)d_out;

  hipLaunchKernelGGL(wpack_kernel, dim3(768), dim3(256), 0, stream,
                     Wq, Wk, Wv, wsp);
  hipLaunchKernelGGL(proj_gemm_f32a, dim3(1536), dim3(256), 0, stream,
                     q, k, v, wsp, qp, kp, vt);
  hipLaunchKernelGGL(attn_kernel, dim3(512), dim3(256), 0, stream,
                     qp, kp, vt, out);
}